// Round 3
// baseline (252.616 us; speedup 1.0000x reference)
//
#include <hip/hip_runtime.h>

// Trilerp of 3 feature levels + mesh concat, with spatial bucketing.
//
// Pipeline (all on `stream`, scratch in d_ws):
//   1. zero_kernel     : clear bucket histogram (ws is poisoned every launch)
//   2. hist_kernel     : count points per coarse 8^3 cell (per batch)
//   3. scan_kernel     : exclusive scan of 1024 buckets (one block)
//   4. scatter_kernel  : counting-sort point ids into perm[] (b encoded in top bits)
//   5. trilerp_main    : gather in bucket order -> waves touch the same feature
//                        lines repeatedly (L1/L2 hits instead of L2-miss refetch)
//
// Main kernel: one wave = 2 points. Lane map per point: 0-7 lvl1 (32ch f4),
// 8-23 lvl2 (64ch), 24-55 lvl3 (128ch); lanes 56-58 mesh of point0,
// 59-61 mesh of point1. Output written at ORIGINAL point positions, so the
// permutation never changes results.

#define BUCK_AXIS 8
#define BUCK_PER_BATCH 512    // 8^3
#define MAX_BUCKETS 1024      // scan kernel capacity (B=2)

__device__ __forceinline__ int point_batch(int p, int N) {
    int b = 0;
    while (p >= N) { p -= N; ++b; }   // B is tiny (2); avoids 32-bit div
    return b;
}

__device__ __forceinline__ int bucket_key(const float* __restrict__ coords,
                                          int t, int N) {
    const float cx = coords[t * 3 + 0];
    const float cy = coords[t * 3 + 1];
    const float cz = coords[t * 3 + 2];
    int kx = (int)(cx * (float)BUCK_AXIS);
    int ky = (int)(cy * (float)BUCK_AXIS);
    int kz = (int)(cz * (float)BUCK_AXIS);
    kx = min(max(kx, 0), BUCK_AXIS - 1);
    ky = min(max(ky, 0), BUCK_AXIS - 1);
    kz = min(max(kz, 0), BUCK_AXIS - 1);
    const int b = point_batch(t, N);
    return b * BUCK_PER_BATCH + ((kx << 6) | (ky << 3) | kz);
}

__global__ void zero_kernel(int* __restrict__ hist, int n) {
    const int t = blockIdx.x * blockDim.x + threadIdx.x;
    if (t < n) hist[t] = 0;
}

__global__ void hist_kernel(const float* __restrict__ coords,
                            int* __restrict__ hist, int N, int P) {
    const int t = blockIdx.x * blockDim.x + threadIdx.x;
    if (t >= P) return;
    atomicAdd(&hist[bucket_key(coords, t, N)], 1);
}

__global__ __launch_bounds__(MAX_BUCKETS) void scan_kernel(
    const int* __restrict__ hist, int* __restrict__ ofs, int n) {
    __shared__ int tmp[MAX_BUCKETS];
    const int t = threadIdx.x;
    const int v = (t < n) ? hist[t] : 0;
    tmp[t] = v;
    __syncthreads();
    for (int s = 1; s < MAX_BUCKETS; s <<= 1) {
        const int add = (t >= s) ? tmp[t - s] : 0;
        __syncthreads();
        tmp[t] += add;
        __syncthreads();
    }
    if (t < n) ofs[t] = tmp[t] - v;   // exclusive scan
}

__global__ void scatter_kernel(const float* __restrict__ coords,
                               int* __restrict__ ofs, int* __restrict__ perm,
                               int N, int P) {
    const int t = blockIdx.x * blockDim.x + threadIdx.x;
    if (t >= P) return;
    const int key = bucket_key(coords, t, N);
    const int b   = key >= BUCK_PER_BATCH;          // B<=2 path; general below
    const int idx = atomicAdd(&ofs[key], 1);
    perm[idx] = t | (b << 28);                      // encode batch in top bits
}

__device__ __forceinline__ float4 lerpw(const float4 a, const float4 b,
                                        float w, float w2) {
    float4 r;
    r.x = a.x * w + b.x * w2;
    r.y = a.y * w + b.y * w2;
    r.z = a.z * w + b.z * w2;
    r.w = a.w * w + b.w * w2;
    return r;
}

__global__ __launch_bounds__(256) void trilerp_main(
    const float* __restrict__ f1,      // [B,64,64,64,32]
    const float* __restrict__ f2,      // [B,32,32,32,64]
    const float* __restrict__ f3,      // [B,16,16,16,128]
    const float* __restrict__ coords,  // [B,N,3]
    const float* __restrict__ meshf,   // [B,N,3]
    float* __restrict__ out,           // [B,N,227]
    const int* __restrict__ perm,      // nullptr -> identity order
    int N, int P)
{
    const int lane = threadIdx.x & 63;
    const int w    = (blockIdx.x * 256 + threadIdx.x) >> 6;
    const int i0   = w * 2;
    if (i0 >= P) return;
    const bool has1 = (i0 + 1) < P;

    int pts[2], bs[2];
    if (perm) {
        const int e0 = perm[i0];
        const int e1 = has1 ? perm[i0 + 1] : e0;
        pts[0] = e0 & 0x0FFFFFFF;  bs[0] = e0 >> 28;
        pts[1] = e1 & 0x0FFFFFFF;  bs[1] = e1 >> 28;
    } else {
        pts[0] = i0;                       bs[0] = point_batch(pts[0], N);
        pts[1] = has1 ? (i0 + 1) : i0;     bs[1] = point_batch(pts[1], N);
    }

    if (lane >= 56) {                       // mesh passthrough, both points
        const int i = lane - 56;            // 0..7
        if (i < 6) {
            const int pi = i / 3;
            const int ch = i - pi * 3;
            if (pi == 0 || has1) {
                const int p = pts[pi];
                __builtin_nontemporal_store(meshf[p * 3 + ch],
                                            &out[p * 227 + 224 + ch]);
            }
        }
        return;
    }

    // level params by lane
    const float4* fp; int D, C4, c4g, oc;
    if (lane < 8)       { fp = (const float4*)f1; D = 64; C4 = 8;  c4g = lane;      oc = lane * 4;             }
    else if (lane < 24) { fp = (const float4*)f2; D = 32; C4 = 16; c4g = lane - 8;  oc = 32 + (lane - 8) * 4;  }
    else                { fp = (const float4*)f3; D = 16; C4 = 32; c4g = lane - 24; oc = 96 + (lane - 24) * 4; }

    const float scale = (float)D;                    // 0.5^p * 128 == D
    const float hi    = (float)((double)D - 1.01);   // matches Python
    const int   vol4  = D * D * D * C4;

    float4 v[2][8];
    float wxa[2], wxb[2], wya[2], wyb[2], wza[2], wzb[2];

    #pragma unroll
    for (int q = 0; q < 2; ++q) {
        const int p = pts[q];
        const float cx = coords[p * 3 + 0];
        const float cy = coords[p * 3 + 1];
        const float cz = coords[p * 3 + 2];

        const float ix = fminf(fmaxf(cx * scale, 0.01f), hi);
        const float iy = fminf(fmaxf(cy * scale, 0.01f), hi);
        const float iz = fminf(fmaxf(cz * scale, 0.01f), hi);

        const float x1f = floorf(ix), x2f = ceilf(ix);
        const float y1f = floorf(iy), y2f = ceilf(iy);
        const float z1f = floorf(iz), z2f = ceilf(iz);
        const int x1 = (int)x1f, x2 = (int)x2f;
        const int y1 = (int)y1f, y2 = (int)y2f;
        const int z1 = (int)z1f, z2 = (int)z2f;

        wxa[q] = ix - x1f; wxb[q] = x2f - ix;
        wya[q] = iy - y1f; wyb[q] = y2f - iy;
        wza[q] = iz - z1f; wzb[q] = z2f - iz;

        const int base4 = bs[q] * vol4 + c4g;
        #define IDX(X, Y, Z) (base4 + (((X) * D + (Y)) * D + (Z)) * C4)
        v[q][0] = fp[IDX(x1, y1, z1)];
        v[q][1] = fp[IDX(x2, y1, z1)];
        v[q][2] = fp[IDX(x1, y2, z1)];
        v[q][3] = fp[IDX(x2, y2, z1)];
        v[q][4] = fp[IDX(x1, y1, z2)];
        v[q][5] = fp[IDX(x2, y1, z2)];
        v[q][6] = fp[IDX(x1, y2, z2)];
        v[q][7] = fp[IDX(x2, y2, z2)];
        #undef IDX
    }

    #pragma unroll
    for (int q = 0; q < 2; ++q) {
        if (q == 1 && !has1) break;
        const float4 lx1a = lerpw(v[q][1], v[q][0], wxa[q], wxb[q]);
        const float4 lx2a = lerpw(v[q][3], v[q][2], wxa[q], wxb[q]);
        const float4 ly1  = lerpw(lx2a,    lx1a,    wya[q], wyb[q]);
        const float4 lx1b = lerpw(v[q][5], v[q][4], wxa[q], wxb[q]);
        const float4 lx2b = lerpw(v[q][7], v[q][6], wxa[q], wxb[q]);
        const float4 ly2  = lerpw(lx2b,    lx1b,    wya[q], wyb[q]);
        const float4 r    = lerpw(ly2,     ly1,     wza[q], wzb[q]);

        float* o = out + pts[q] * 227 + oc;
        __builtin_nontemporal_store(r.x, o + 0);
        __builtin_nontemporal_store(r.y, o + 1);
        __builtin_nontemporal_store(r.z, o + 2);
        __builtin_nontemporal_store(r.w, o + 3);
    }
}

extern "C" void kernel_launch(void* const* d_in, const int* in_sizes, int n_in,
                              void* d_out, int out_size, void* d_ws, size_t ws_size,
                              hipStream_t stream) {
    const float* f1     = (const float*)d_in[1];
    const float* f2     = (const float*)d_in[2];
    const float* f3     = (const float*)d_in[3];
    const float* coords = (const float*)d_in[5];
    const float* meshf  = (const float*)d_in[6];
    float* out = (float*)d_out;

    const int B = in_sizes[1] / (64 * 64 * 64 * 32);
    const int N = in_sizes[5] / (B * 3);
    const int P = B * N;

    int* hist = (int*)d_ws;
    int* ofs  = hist + MAX_BUCKETS;
    int* perm = hist + 2 * MAX_BUCKETS;
    const size_t need = (size_t)(2 * MAX_BUCKETS + P) * sizeof(int);
    const int nb = B * BUCK_PER_BATCH;
    const bool useSort = (ws_size >= need) && (nb <= MAX_BUCKETS);

    if (useSort) {
        zero_kernel<<<dim3((nb + 255) / 256), dim3(256), 0, stream>>>(hist, nb);
        hist_kernel<<<dim3((P + 255) / 256), dim3(256), 0, stream>>>(coords, hist, N, P);
        scan_kernel<<<dim3(1), dim3(MAX_BUCKETS), 0, stream>>>(hist, ofs, nb);
        scatter_kernel<<<dim3((P + 255) / 256), dim3(256), 0, stream>>>(coords, ofs, perm, N, P);
    }

    trilerp_main<<<dim3((P + 7) / 8), dim3(256), 0, stream>>>(
        f1, f2, f3, coords, meshf, out, useSort ? perm : nullptr, N, P);
}

// Round 4
// 214.720 us; speedup vs baseline: 1.1765x; 1.1765x over previous
//
#include <hip/hip_runtime.h>

// Trilerp of 3 feature levels + mesh concat. Single kernel, no preprocessing
// (R3 showed the counting-sort pipeline costs ~41us to save 6us -- dropped).
//
// One WAVE = 2 points. Lane map per point: 0-7 lvl1 (32ch, float4/lane),
// 8-23 lvl2 (64ch), 24-55 lvl3 (128ch); lanes 56-61 mesh passthrough
// (3 ch x 2 points), 62-63 idle.
//
// Key change vs R3: ALL 16 corner gathers (both points) are issued before any
// lerp math, enforced by sched_barrier(0). R3's VGPR=32 proved the compiler
// was sinking point-1 loads below point-0 math (only 8 loads in flight);
// we trade VGPRs (~90) for 2x memory-level parallelism per wave.

__device__ __forceinline__ int point_batch(int p, int N) {
    int b = 0;
    while (p >= N) { p -= N; ++b; }   // B is tiny (2)
    return b;
}

__device__ __forceinline__ float4 lerpw(const float4 a, const float4 b,
                                        float w, float w2) {
    float4 r;
    r.x = a.x * w + b.x * w2;
    r.y = a.y * w + b.y * w2;
    r.z = a.z * w + b.z * w2;
    r.w = a.w * w + b.w * w2;
    return r;
}

__global__ __launch_bounds__(256) void trilerp_kernel(
    const float* __restrict__ f1,      // [B,64,64,64,32]
    const float* __restrict__ f2,      // [B,32,32,32,64]
    const float* __restrict__ f3,      // [B,16,16,16,128]
    const float* __restrict__ coords,  // [B,N,3]
    const float* __restrict__ meshf,   // [B,N,3]
    float* __restrict__ out,           // [B,N,227]
    int N, int P)
{
    const int lane = threadIdx.x & 63;
    const int wv   = (blockIdx.x * 256 + threadIdx.x) >> 6;
    const int i0   = wv * 2;
    if (i0 >= P) return;
    const bool has1 = (i0 + 1) < P;

    const int pts[2] = { i0, has1 ? (i0 + 1) : i0 };

    if (lane >= 56) {                       // mesh passthrough, both points
        const int i = lane - 56;            // 0..7
        if (i < 6) {
            const int pi = i >= 3;
            const int ch = i - pi * 3;
            if (pi == 0 || has1) {
                const int p = pts[pi];
                __builtin_nontemporal_store(meshf[p * 3 + ch],
                                            &out[p * 227 + 224 + ch]);
            }
        }
        return;
    }

    // level params by lane
    const float4* fp; int D, C4, c4g, oc;
    if (lane < 8)       { fp = (const float4*)f1; D = 64; C4 = 8;  c4g = lane;      oc = lane * 4;             }
    else if (lane < 24) { fp = (const float4*)f2; D = 32; C4 = 16; c4g = lane - 8;  oc = 32 + (lane - 8) * 4;  }
    else                { fp = (const float4*)f3; D = 16; C4 = 32; c4g = lane - 24; oc = 96 + (lane - 24) * 4; }

    const float scale = (float)D;                    // 0.5^p * 128 == D
    const float hi    = (float)((double)D - 1.01);   // matches Python
    const int   vol4  = D * D * D * C4;

    // ---- phase 1: addresses + all 16 loads ----
    int   idx[2][8];
    float wxa[2], wxb[2], wya[2], wyb[2], wza[2], wzb[2];

    #pragma unroll
    for (int q = 0; q < 2; ++q) {
        const int p = pts[q];
        const float cx = coords[p * 3 + 0];
        const float cy = coords[p * 3 + 1];
        const float cz = coords[p * 3 + 2];

        const float ix = fminf(fmaxf(cx * scale, 0.01f), hi);
        const float iy = fminf(fmaxf(cy * scale, 0.01f), hi);
        const float iz = fminf(fmaxf(cz * scale, 0.01f), hi);

        const float x1f = floorf(ix), x2f = ceilf(ix);
        const float y1f = floorf(iy), y2f = ceilf(iy);
        const float z1f = floorf(iz), z2f = ceilf(iz);
        const int x1 = (int)x1f, x2 = (int)x2f;
        const int y1 = (int)y1f, y2 = (int)y2f;
        const int z1 = (int)z1f, z2 = (int)z2f;

        wxa[q] = ix - x1f; wxb[q] = x2f - ix;
        wya[q] = iy - y1f; wyb[q] = y2f - iy;
        wza[q] = iz - z1f; wzb[q] = z2f - iz;

        const int base4 = point_batch(p, N) * vol4 + c4g;
        #define IDX(X, Y, Z) (base4 + (((X) * D + (Y)) * D + (Z)) * C4)
        idx[q][0] = IDX(x1, y1, z1);
        idx[q][1] = IDX(x2, y1, z1);
        idx[q][2] = IDX(x1, y2, z1);
        idx[q][3] = IDX(x2, y2, z1);
        idx[q][4] = IDX(x1, y1, z2);
        idx[q][5] = IDX(x2, y1, z2);
        idx[q][6] = IDX(x1, y2, z2);
        idx[q][7] = IDX(x2, y2, z2);
        #undef IDX
    }

    float4 v[2][8];
    #pragma unroll
    for (int q = 0; q < 2; ++q)
        #pragma unroll
        for (int j = 0; j < 8; ++j)
            v[q][j] = fp[idx[q][j]];

    // Pin the schedule: nothing (esp. the lerp math) may move above this
    // point, so all 16 gathers are in flight before the first s_waitcnt.
    __builtin_amdgcn_sched_barrier(0);

    // ---- phase 2: math + stores ----
    #pragma unroll
    for (int q = 0; q < 2; ++q) {
        if (q == 1 && !has1) break;
        const float4 lx1a = lerpw(v[q][1], v[q][0], wxa[q], wxb[q]);
        const float4 lx2a = lerpw(v[q][3], v[q][2], wxa[q], wxb[q]);
        const float4 ly1  = lerpw(lx2a,    lx1a,    wya[q], wyb[q]);
        const float4 lx1b = lerpw(v[q][5], v[q][4], wxa[q], wxb[q]);
        const float4 lx2b = lerpw(v[q][7], v[q][6], wxa[q], wxb[q]);
        const float4 ly2  = lerpw(lx2b,    lx1b,    wya[q], wyb[q]);
        const float4 r    = lerpw(ly2,     ly1,     wza[q], wzb[q]);

        float* o = out + pts[q] * 227 + oc;
        __builtin_nontemporal_store(r.x, o + 0);
        __builtin_nontemporal_store(r.y, o + 1);
        __builtin_nontemporal_store(r.z, o + 2);
        __builtin_nontemporal_store(r.w, o + 3);
    }
}

extern "C" void kernel_launch(void* const* d_in, const int* in_sizes, int n_in,
                              void* d_out, int out_size, void* d_ws, size_t ws_size,
                              hipStream_t stream) {
    const float* f1     = (const float*)d_in[1];
    const float* f2     = (const float*)d_in[2];
    const float* f3     = (const float*)d_in[3];
    const float* coords = (const float*)d_in[5];
    const float* meshf  = (const float*)d_in[6];
    float* out = (float*)d_out;

    const int B = in_sizes[1] / (64 * 64 * 64 * 32);
    const int N = in_sizes[5] / (B * 3);
    const int P = B * N;

    trilerp_kernel<<<dim3((P + 7) / 8), dim3(256), 0, stream>>>(
        f1, f2, f3, coords, meshf, out, N, P);
}

// Round 5
// 212.348 us; speedup vs baseline: 1.1896x; 1.0112x over previous
//
#include <hip/hip_runtime.h>

// Trilerp of 3 feature levels + mesh concat. Level-specialized waves:
//   lvl1 (64^3 x 32ch):  8 lanes/point  -> 8 points/wave
//   lvl2 (32^3 x 64ch): 16 lanes/point  -> 4 points/wave
//   lvl3 (16^3 x128ch): 32 lanes/point  -> 2 points/wave
// One grid; contiguous blockIdx ranges pick the level (wave-uniform branch).
// Each wave issues its 8 corner gathers (float4/lane, 32 VGPRs of data) and
// its single memory round-trip retires 8/4/2 points -- vs 2 in the previous
// mixed-lane layout. Per-point weight/address math replication drops from
// 64 lanes to 8/16/32 lanes.
// Output layout: [B,N,227] = [32 | 64 | 128 | 3 mesh].

__device__ __forceinline__ int point_batch(int p, int N) {
    int b = 0;
    while (p >= N) { p -= N; ++b; }   // B is tiny (2)
    return b;
}

__device__ __forceinline__ float4 lerpw(const float4 a, const float4 b,
                                        float w, float w2) {
    float4 r;
    r.x = a.x * w + b.x * w2;
    r.y = a.y * w + b.y * w2;
    r.z = a.z * w + b.z * w2;
    r.w = a.w * w + b.w * w2;
    return r;
}

// D: grid dim; LPP: lanes per point (== C/4); OCB: output channel base.
template<int D, int LPP, int OCB>
__device__ __forceinline__ void do_level(const float4* __restrict__ fp,
                                         const float* __restrict__ coords,
                                         float* __restrict__ out,
                                         int pBase, int N, int P)
{
    const int tid  = threadIdx.x;
    const int lane = tid & 63;
    const int wv   = tid >> 6;
    const int p    = pBase + wv * (64 / LPP) + (lane / LPP);
    const int c4   = lane & (LPP - 1);
    if (p >= P) return;

    // coords: identical address within each LPP-lane group -> broadcast fetch
    const float cx = coords[p * 3 + 0];
    const float cy = coords[p * 3 + 1];
    const float cz = coords[p * 3 + 2];

    const float scale = (float)D;                    // 0.5^pow * 128 == D
    const float hi    = (float)((double)D - 1.01);   // matches Python

    const float ix = fminf(fmaxf(cx * scale, 0.01f), hi);
    const float iy = fminf(fmaxf(cy * scale, 0.01f), hi);
    const float iz = fminf(fmaxf(cz * scale, 0.01f), hi);

    const float x1f = floorf(ix), x2f = ceilf(ix);
    const float y1f = floorf(iy), y2f = ceilf(iy);
    const float z1f = floorf(iz), z2f = ceilf(iz);
    const int x1 = (int)x1f, x2 = (int)x2f;
    const int y1 = (int)y1f, y2 = (int)y2f;
    const int z1 = (int)z1f, z2 = (int)z2f;

    // Reference weight convention: wx multiplies the x2 (ceil) sample.
    const float wx = ix - x1f, wx2 = x2f - ix;
    const float wy = iy - y1f, wy2 = y2f - iy;
    const float wz = iz - z1f, wz2 = z2f - iz;

    const int base4 = point_batch(p, N) * (D * D * D * LPP) + c4;
    #define IDX(X, Y, Z) (base4 + (((X) * D + (Y)) * D + (Z)) * LPP)
    const float4 v111 = fp[IDX(x1, y1, z1)];
    const float4 v211 = fp[IDX(x2, y1, z1)];
    const float4 v121 = fp[IDX(x1, y2, z1)];
    const float4 v221 = fp[IDX(x2, y2, z1)];
    const float4 v112 = fp[IDX(x1, y1, z2)];
    const float4 v212 = fp[IDX(x2, y1, z2)];
    const float4 v122 = fp[IDX(x1, y2, z2)];
    const float4 v222 = fp[IDX(x2, y2, z2)];
    #undef IDX

    const float4 lx1a = lerpw(v211, v111, wx, wx2);
    const float4 lx2a = lerpw(v221, v121, wx, wx2);
    const float4 ly1  = lerpw(lx2a, lx1a, wy, wy2);
    const float4 lx1b = lerpw(v212, v112, wx, wx2);
    const float4 lx2b = lerpw(v222, v122, wx, wx2);
    const float4 ly2  = lerpw(lx2b, lx1b, wy, wy2);
    const float4 r    = lerpw(ly2,  ly1,  wz, wz2);

    float* o = out + p * 227 + OCB + c4 * 4;
    __builtin_nontemporal_store(r.x, o + 0);
    __builtin_nontemporal_store(r.y, o + 1);
    __builtin_nontemporal_store(r.z, o + 2);
    __builtin_nontemporal_store(r.w, o + 3);
}

__global__ __launch_bounds__(256) void trilerp_kernel(
    const float* __restrict__ f1,      // [B,64,64,64,32]
    const float* __restrict__ f2,      // [B,32,32,32,64]
    const float* __restrict__ f3,      // [B,16,16,16,128]
    const float* __restrict__ coords,  // [B,N,3]
    const float* __restrict__ meshf,   // [B,N,3]
    float* __restrict__ out,           // [B,N,227]
    int N, int P, int nb1, int nb2, int nb3)
{
    const int blk = blockIdx.x;
    if (blk < nb1) {
        do_level<64, 8, 0>((const float4*)f1, coords, out, blk * 32, N, P);
    } else if (blk < nb1 + nb2) {
        do_level<32, 16, 32>((const float4*)f2, coords, out, (blk - nb1) * 16, N, P);
    } else if (blk < nb1 + nb2 + nb3) {
        do_level<16, 32, 96>((const float4*)f3, coords, out,
                             (blk - nb1 - nb2) * 8, N, P);
    } else {
        // mesh passthrough: one thread per element of [B,N,3]
        const int e = (blk - nb1 - nb2 - nb3) * 256 + (int)threadIdx.x;
        if (e < P * 3) {
            const int p = e / 3, c = e - p * 3;
            __builtin_nontemporal_store(meshf[e], &out[p * 227 + 224 + c]);
        }
    }
}

extern "C" void kernel_launch(void* const* d_in, const int* in_sizes, int n_in,
                              void* d_out, int out_size, void* d_ws, size_t ws_size,
                              hipStream_t stream) {
    const float* f1     = (const float*)d_in[1];
    const float* f2     = (const float*)d_in[2];
    const float* f3     = (const float*)d_in[3];
    const float* coords = (const float*)d_in[5];
    const float* meshf  = (const float*)d_in[6];
    float* out = (float*)d_out;

    const int B = in_sizes[1] / (64 * 64 * 64 * 32);
    const int N = in_sizes[5] / (B * 3);
    const int P = B * N;

    const int nb1 = (P + 31) / 32;          // 32 points/block (8 pts/wave)
    const int nb2 = (P + 15) / 16;          // 16 points/block
    const int nb3 = (P + 7) / 8;            //  8 points/block
    const int nbm = (P * 3 + 255) / 256;    // mesh copy blocks
    const int grid = nb1 + nb2 + nb3 + nbm;

    trilerp_kernel<<<dim3(grid), dim3(256), 0, stream>>>(
        f1, f2, f3, coords, meshf, out, N, P, nb1, nb2, nb3);
}